// Round 7
// baseline (106.364 us; speedup 1.0000x reference)
//
#include <hip/hip_runtime.h>

constexpr int S = 512, B = 8192, H = 5;
constexpr float KN1 = -1.44269504088896340736f;   // -log2(e)
constexpr float KN2 = 2.0f * KN1;                 // -2*log2(e)

__device__ __forceinline__ float fexp2(float x) { return __builtin_amdgcn_exp2f(x); }
__device__ __forceinline__ float frcp(float x)  { return __builtin_amdgcn_rcpf(x); }

// ds_swizzle BitMode (within each 32-lane half): src = ((l&and)|or)^xor,
// imm = xor<<10 | or<<5 | and.
#define SWZ(v, imm) __int_as_float(__builtin_amdgcn_ds_swizzle(__float_as_int(v), (imm)))
// DPP row_ror:5 within 16-lane rows: lane l RECEIVES lane (l-5)&15.
#define ROR5(v) __int_as_float(__builtin_amdgcn_mov_dpp(__float_as_int(v), 0x125, 0xF, 0xF, false))

// 32 lanes per chain (2 chains/wave), q = lane&31:
//   q 0-4: i_j (j=q) | 5-9: f_j (c,h state here) | 16-20: g_j | 21-25: o_j
//   q 10-15, 26-31: junk (zero-ish weights; results never read by valid lanes)
// Each lane: ONE gate = 2 x-FMA + 5 h-FMA; ONE exp2+rcp activates all 20
// gates; one more pair does tanh(c). Cross-lane: SWZ xor:16 row-swap gives
// i-lanes g AND f-lanes o in one op; ROR5 moves i*g onto f-lanes; 5 SWZ
// broadcasts distribute h. Weights pre-scaled by -log2e (g rows -2log2e);
// cell state kept scaled (CS = c*KN2); g epilogue folds KN2.
// 8192 chains * 32 = 262144 threads = 4096 waves = 4 waves/SIMD.
__global__ __launch_bounds__(256, 4) void lstm_kernel(
    const float* __restrict__ x,      // [S,B,2]
    const float* __restrict__ W_ih,   // [4H,2]
    const float* __restrict__ W_hh,   // [4H,H]
    const float* __restrict__ b_ih,   // [4H]
    const float* __restrict__ b_hh,   // [4H]
    const float* __restrict__ W_lin,  // [1,H]
    const float* __restrict__ b_lin,  // [1]
    float* __restrict__ out)          // [B,1]
{
  const int tid   = blockIdx.x * blockDim.x + threadIdx.x;
  const int chain = tid >> 5;
  const int q     = tid & 31;

  // Gate type t (0=i,1=f,2=g,3=o) and unit j for this lane.
  int t, j;
  if      (q < 5)  { t = 0; j = q; }
  else if (q < 10) { t = 1; j = q - 5; }
  else if (q < 16) { t = 0; j = 0; }        // junk lane
  else if (q < 21) { t = 2; j = q - 16; }
  else if (q < 26) { t = 3; j = q - 21; }
  else             { t = 0; j = 0; }        // junk lane
  const int   r  = t * H + j;
  const float s  = (t == 2) ? KN2 : KN1;    // g rows scaled by -2log2e
  const float eA = (t == 2) ? 2.0f * KN2 : 1.0f;  // act = rv*eA + eB:
  const float eB = (t == 2) ? -KN2 : 0.0f;        //  σ on i,f,o ; g*KN2 on g

  const float wx0 = W_ih[r * 2 + 0] * s;
  const float wx1 = W_ih[r * 2 + 1] * s;
  float wh[H];
  #pragma unroll
  for (int k = 0; k < H; ++k) wh[k] = W_hh[r * H + k] * s;
  const float bb = (b_ih[r] + b_hh[r]) * s;

  float CS = 0.0f, h = 0.0f;          // valid on f-lanes (q in [5,10))
  float hg[H] = {0, 0, 0, 0, 0};      // broadcast h vector (all lanes)

  const float2* __restrict__ x2 = (const float2*)x;

  auto step = [&](float2 xv) {
    float a = fmaf(xv.x, wx0, bb);
    a = fmaf(xv.y, wx1, a);
    #pragma unroll
    for (int k = 0; k < H; ++k) a = fmaf(hg[k], wh[k], a);
    const float e   = fexp2(a);
    const float rv  = frcp(1.0f + e);
    const float act = fmaf(rv, eA, eB);     // i/f/o: σ ; g-lane: g*KN2
    const float asw = SWZ(act, 0x401F);     // xor16: i-lane<-g*KN2, f-lane<-o
    const float p   = act * asw;            // i-lane: i*g*KN2
    const float pr  = ROR5(p);              // f-lane <- i-lane's p
    CS = fmaf(act, CS, pr);                 // f-lane: f*CS + i*g*KN2
    const float et = fexp2(CS);             // exp(-2c)
    const float rt = frcp(1.0f + et);       // σ(2c)
    const float o2 = asw + asw;             // 2o on f-lane
    h = fmaf(rt, o2, -asw);                 // o*(2σ(2c)-1) = o*tanh(c)
    hg[0] = SWZ(h, 0x0A0);                  // broadcast lane 5+k to all 32
    hg[1] = SWZ(h, 0x0C0);
    hg[2] = SWZ(h, 0x0E0);
    hg[3] = SWZ(h, 0x100);
    hg[4] = SWZ(h, 0x120);
  };

  // Ping-pong register prefetch of x, 4 steps deep.
  constexpr int CH = 4;
  float2 buf0[CH], buf1[CH];
  #pragma unroll
  for (int u = 0; u < CH; ++u) buf0[u] = x2[(size_t)u * B + chain];

  for (int t0 = 0; t0 < S; t0 += 2 * CH) {
    #pragma unroll
    for (int u = 0; u < CH; ++u) buf1[u] = x2[(size_t)(t0 + CH + u) * B + chain];
    #pragma unroll
    for (int u = 0; u < CH; ++u) step(buf0[u]);
    if (t0 + 2 * CH < S) {
      #pragma unroll
      for (int u = 0; u < CH; ++u) buf0[u] = x2[(size_t)(t0 + 2 * CH + u) * B + chain];
    }
    #pragma unroll
    for (int u = 0; u < CH; ++u) step(buf1[u]);
  }

  // out[chain] = sum_j h_j*W_lin[j] + b_lin; h_j on f-lanes. Butterfly over
  // all 32 lanes (junk lanes contribute 0), then lane q==0 writes.
  float pv = (q >= 5 && q < 10) ? h * W_lin[q - 5] : 0.0f;
  pv += SWZ(pv, 0x041F);   // xor 1
  pv += SWZ(pv, 0x081F);   // xor 2
  pv += SWZ(pv, 0x101F);   // xor 4
  pv += SWZ(pv, 0x201F);   // xor 8
  pv += SWZ(pv, 0x401F);   // xor 16
  if (q == 0) out[chain] = pv + b_lin[0];
}

extern "C" void kernel_launch(void* const* d_in, const int* in_sizes, int n_in,
                              void* d_out, int out_size, void* d_ws, size_t ws_size,
                              hipStream_t stream) {
  const float* x     = (const float*)d_in[0];
  const float* W_ih  = (const float*)d_in[1];
  const float* W_hh  = (const float*)d_in[2];
  const float* b_ih  = (const float*)d_in[3];
  const float* b_hh  = (const float*)d_in[4];
  const float* W_lin = (const float*)d_in[5];
  const float* b_lin = (const float*)d_in[6];
  float* out = (float*)d_out;

  const int threads = B * 32;          // 262144 -> 4096 waves -> 4/SIMD
  dim3 grid(threads / 256), block(256);
  hipLaunchKernelGGL(lstm_kernel, grid, block, 0, stream,
                     x, W_ih, W_hh, b_ih, b_hh, W_lin, b_lin, out);
}

// Round 8
// 87.545 us; speedup vs baseline: 1.2150x; 1.2150x over previous
//
#include <hip/hip_runtime.h>

typedef float v2f __attribute__((ext_vector_type(2)));

constexpr int S = 512, B = 8192, H = 5;
constexpr float KN1 = -1.44269504088896340736f;   // -log2(e)
constexpr float KN2 = 2.0f * KN1;                 // -2*log2(e)

__device__ __forceinline__ float fexp2(float x) { return __builtin_amdgcn_exp2f(x); }
__device__ __forceinline__ float frcp(float x)  { return __builtin_amdgcn_rcpf(x); }

// ds_swizzle BitMode: src = ((l&and)|or)^xor ; imm = xor<<10 | or<<5 | and
#define SWZ(v, imm) __int_as_float(__builtin_amdgcn_ds_swizzle(__float_as_int(v), (imm)))
// DPP row_ror:8 within 16-lane rows: lane l RECEIVES lane (l-8)&15 (== (l+8)&15).
#define ROR8(v) __int_as_float(__builtin_amdgcn_mov_dpp(__float_as_int(v), 0x128, 0xF, 0xF, false))

// Two independent chains (streams P,Q) per 16-lane group, same timestep,
// software-interleaved so their dependency chains fill each other's stalls.
//   P (R3 map):   u0 owns {i,g}, u1 owns {f,o}; CS_P, h_P valid on u1.
//   Q (mirrored): u0 owns {f,o}, u1 owns {i,g}; CS_Q, h_Q valid on u0.
// Mirror => CS_P and CS_Q live in DISJOINT lane halves: one cndmask + one
// shared exp2/rcp pair computes both streams' tanh (10 trans per step-pair
// instead of 12), with zero lane moves.
// Weights pre-scaled by -log2e (g rows -2log2e); CS kept scaled (c*KN2);
// g epilogue folds KN2 (gK = g*KN2 on g-lanes, = o on o-lanes);
// h = fma(rt, 2o, -o) = o*tanh(c).
// 4096 groups * 16 = 65536 threads = 1024 waves = 1 wave/SIMD; stall hiding
// comes from in-wave ILP between P and Q instead of TLP.
__global__ __launch_bounds__(256, 1) void lstm_kernel(
    const float* __restrict__ x,      // [S,B,2]
    const float* __restrict__ W_ih,   // [4H,2]
    const float* __restrict__ W_hh,   // [4H,H]
    const float* __restrict__ b_ih,   // [4H]
    const float* __restrict__ b_hh,   // [4H]
    const float* __restrict__ W_lin,  // [1,H]
    const float* __restrict__ b_lin,  // [1]
    float* __restrict__ out)          // [B,1]
{
  const int tid = blockIdx.x * blockDim.x + threadIdx.x;
  const int g   = tid >> 4;            // group -> chains 2g (P), 2g+1 (Q)
  const int l   = tid & 15;
  const int u   = l >> 3;
  const int j   = l & 7;
  const int jm  = (j < H) ? j : H - 1;

  // P rows: act1 = i(u0)/f(u1), act2 = g(u0)/o(u1)
  const int r1P = (u ? H : 0) + jm;
  const int r2P = (u ? 3 * H : 2 * H) + jm;
  const float s2P = u ? KN1 : KN2;
  const float eAP = u ? 1.0f : 2.0f * KN2;
  const float eBP = u ? 0.0f : -KN2;
  // Q rows (mirrored): act1 = f(u0)/i(u1), act2 = o(u0)/g(u1)
  const int r1Q = (u ? 0 : H) + jm;
  const int r2Q = (u ? 2 * H : 3 * H) + jm;
  const float s2Q = u ? KN2 : KN1;
  const float eAQ = u ? 2.0f * KN2 : 1.0f;
  const float eBQ = u ? -KN2 : 0.0f;

  v2f wx0P = {W_ih[r1P * 2 + 0] * KN1, W_ih[r2P * 2 + 0] * s2P};
  v2f wx1P = {W_ih[r1P * 2 + 1] * KN1, W_ih[r2P * 2 + 1] * s2P};
  v2f wx0Q = {W_ih[r1Q * 2 + 0] * KN1, W_ih[r2Q * 2 + 0] * s2Q};
  v2f wx1Q = {W_ih[r1Q * 2 + 1] * KN1, W_ih[r2Q * 2 + 1] * s2Q};
  v2f whP[H], whQ[H];
  #pragma unroll
  for (int k = 0; k < H; ++k) {
    whP[k] = (v2f){W_hh[r1P * H + k] * KN1, W_hh[r2P * H + k] * s2P};
    whQ[k] = (v2f){W_hh[r1Q * H + k] * KN1, W_hh[r2Q * H + k] * s2Q};
  }
  const v2f bbP = {(b_ih[r1P] + b_hh[r1P]) * KN1, (b_ih[r2P] + b_hh[r2P]) * s2P};
  const v2f bbQ = {(b_ih[r1Q] + b_hh[r1Q]) * KN1, (b_ih[r2Q] + b_hh[r2Q]) * s2Q};

  float CSP = 0.f, hP = 0.f;           // valid on u1
  float CSQ = 0.f, hQ = 0.f;           // valid on u0
  float hgP[H] = {0, 0, 0, 0, 0};
  float hgQ[H] = {0, 0, 0, 0, 0};

  const float4* __restrict__ x4 = (const float4*)x;  // [S][B/2]: {xP, xQ}

  auto step = [&](float4 xv) {
    // --- gate pre-activations, P and Q interleaved (independent) ---
    v2f aP = bbP, aQ = bbQ;
    aP = __builtin_elementwise_fma((v2f){xv.x, xv.x}, wx0P, aP);
    aQ = __builtin_elementwise_fma((v2f){xv.z, xv.z}, wx0Q, aQ);
    aP = __builtin_elementwise_fma((v2f){xv.y, xv.y}, wx1P, aP);
    aQ = __builtin_elementwise_fma((v2f){xv.w, xv.w}, wx1Q, aQ);
    #pragma unroll
    for (int k = 0; k < H; ++k) {
      aP = __builtin_elementwise_fma((v2f){hgP[k], hgP[k]}, whP[k], aP);
      aQ = __builtin_elementwise_fma((v2f){hgQ[k], hgQ[k]}, whQ[k], aQ);
    }
    // --- activations (8 independent trans values -> pipelined) ---
    const float e1P = fexp2(aP.x), e2P = fexp2(aP.y);
    const float e1Q = fexp2(aQ.x), e2Q = fexp2(aQ.y);
    const float v1P = frcp(1.f + e1P), r2Pv = frcp(1.f + e2P);
    const float v1Q = frcp(1.f + e1Q), r2Qv = frcp(1.f + e2Q);
    const float gKP = fmaf(r2Pv, eAP, eBP);   // P: g*KN2(u0) / o(u1)
    const float gKQ = fmaf(r2Qv, eAQ, eBQ);   // Q: o(u0) / g*KN2(u1)
    const float pP  = v1P * gKP;              // P: i*g*KN2 on u0
    const float pQ  = v1Q * gKQ;              // Q: i*g*KN2 on u1
    const float prP = ROR8(pP);               // -> u1
    const float prQ = ROR8(pQ);               // -> u0
    CSP = fmaf(v1P, CSP, prP);                // P: f*CS + i*g*KN2 (u1)
    CSQ = fmaf(v1Q, CSQ, prQ);                // Q: same on u0
    // --- shared tanh: disjoint lane halves, one trans pair for both ---
    const float CSm = u ? CSP : CSQ;
    const float et  = fexp2(CSm);             // exp(-2c)
    const float rt  = frcp(1.f + et);         // sigma(2c)
    hP = fmaf(rt, gKP + gKP, -gKP);           // o*tanh(c), valid u1
    hQ = fmaf(rt, gKQ + gKQ, -gKQ);           // o*tanh(c), valid u0
    // --- h broadcasts (group-local) ---
    hgP[0] = SWZ(hP, 0x110); hgQ[0] = SWZ(hQ, 0x010);
    hgP[1] = SWZ(hP, 0x130); hgQ[1] = SWZ(hQ, 0x030);
    hgP[2] = SWZ(hP, 0x150); hgQ[2] = SWZ(hQ, 0x050);
    hgP[3] = SWZ(hP, 0x170); hgQ[3] = SWZ(hQ, 0x070);
    hgP[4] = SWZ(hP, 0x190); hgQ[4] = SWZ(hQ, 0x090);
  };

  // Ping-pong register prefetch of x, 4 steps deep (float4 = both chains).
  constexpr int CH = 4;
  float4 buf0[CH], buf1[CH];
  #pragma unroll
  for (int t = 0; t < CH; ++t) buf0[t] = x4[(size_t)t * (B / 2) + g];

  for (int t0 = 0; t0 < S; t0 += 2 * CH) {
    #pragma unroll
    for (int t = 0; t < CH; ++t) buf1[t] = x4[(size_t)(t0 + CH + t) * (B / 2) + g];
    #pragma unroll
    for (int t = 0; t < CH; ++t) step(buf0[t]);
    if (t0 + 2 * CH < S) {
      #pragma unroll
      for (int t = 0; t < CH; ++t) buf0[t] = x4[(size_t)(t0 + 2 * CH + t) * (B / 2) + g];
    }
    #pragma unroll
    for (int t = 0; t < CH; ++t) step(buf1[t]);
  }

  // Output: P's h on u1 half, Q's h on u0 half; butterfly xor{1,2,4} sums
  // each 8-lane half independently; lane 8 writes P (chain 2g), lane 0
  // writes Q (chain 2g+1).
  float pv = 0.f;
  if (j < H) pv = (u ? hP : hQ) * W_lin[jm];
  pv += SWZ(pv, 0x041F);
  pv += SWZ(pv, 0x081F);
  pv += SWZ(pv, 0x101F);
  if ((tid & 15) == 8) out[2 * g]     = pv + b_lin[0];
  if ((tid & 15) == 0) out[2 * g + 1] = pv + b_lin[0];
}

extern "C" void kernel_launch(void* const* d_in, const int* in_sizes, int n_in,
                              void* d_out, int out_size, void* d_ws, size_t ws_size,
                              hipStream_t stream) {
  const float* x     = (const float*)d_in[0];
  const float* W_ih  = (const float*)d_in[1];
  const float* W_hh  = (const float*)d_in[2];
  const float* b_ih  = (const float*)d_in[3];
  const float* b_hh  = (const float*)d_in[4];
  const float* W_lin = (const float*)d_in[5];
  const float* b_lin = (const float*)d_in[6];
  float* out = (float*)d_out;

  const int threads = (B / 2) * 16;    // 65536 -> 1024 waves -> 1/SIMD
  dim3 grid(threads / 256), block(256);
  hipLaunchKernelGGL(lstm_kernel, grid, block, 0, stream,
                     x, W_ih, W_hh, b_ih, b_hh, W_lin, b_lin, out);
}

// Round 9
// 74.258 us; speedup vs baseline: 1.4323x; 1.1789x over previous
//
#include <hip/hip_runtime.h>

typedef float v2f __attribute__((ext_vector_type(2)));

constexpr int S = 512, B = 8192, H = 5;
constexpr float KN1 = -1.44269504088896340736f;   // -log2(e)
constexpr float KN2 = 2.0f * KN1;                 // -2*log2(e)

__device__ __forceinline__ float fexp2(float x) { return __builtin_amdgcn_exp2f(x); }
__device__ __forceinline__ float frcp(float x)  { return __builtin_amdgcn_rcpf(x); }

// ds_swizzle (epilogue reduction only): imm = xor<<10 | or<<5 | and
#define SWZ(v, imm) __int_as_float(__builtin_amdgcn_ds_swizzle(__float_as_int(v), (imm)))
// DPP, VALU-pipe, all in-group for 8-aligned 8-lane groups:
//   quad_perm[k,k,k,k] (ctrl k*0x55): broadcast lane k of each 4-quad
//   row_half_mirror (ctrl 0x141):      lane l <-> lane (l&~7)|(7-(l&7))
#define DPP(v, ctrl) __int_as_float(__builtin_amdgcn_mov_dpp(__float_as_int(v), (ctrl), 0xF, 0xF, false))

// 8 lanes per chain, lane j owns unit j WHOLLY: all four gates i,f,g,o,
// cell state and h of unit j live in lane j (lanes 5-7 duplicate unit 4 --
// bitwise-identical values, never junk). i*g, c-update, tanh, h are all
// lane-LOCAL; the only cross-lane op is the h-broadcast, done with
// quad_perm + row_half_mirror DPP (VALU pipe, ~12 cy) instead of
// ds_swizzle (LDS pipe, ~120 cy) -- this removes the R2-R8 critical path.
// Gate pairs packed as v2f {i,f} / {g,o} -> v_pk_fma_f32.
// Weights pre-scaled by -log2e (g rows -2log2e); cell state kept SCALED
// (CS = c*KN2); g epilogue folds KN2 (gK = g*KN2); h = fma(rt, 2o, -o).
// 8192 chains * 8 = 65536 threads = 1024 waves = 1 wave/SIMD, issue-bound.
__global__ __launch_bounds__(256, 1) void lstm_kernel(
    const float* __restrict__ x,      // [S,B,2]
    const float* __restrict__ W_ih,   // [4H,2]
    const float* __restrict__ W_hh,   // [4H,H]
    const float* __restrict__ b_ih,   // [4H]
    const float* __restrict__ b_hh,   // [4H]
    const float* __restrict__ W_lin,  // [1,H]
    const float* __restrict__ b_lin,  // [1]
    float* __restrict__ out)          // [B,1]
{
  const int tid   = blockIdx.x * blockDim.x + threadIdx.x;
  const int chain = tid >> 3;
  const int j     = tid & 7;
  const int jm    = (j < H) ? j : H - 1;

  const int ri = jm, rf = H + jm, rg = 2 * H + jm, ro = 3 * H + jm;

  // acc1 = {i-row, f-row} (both KN1); acc2 = {g-row (KN2), o-row (KN1)}.
  const v2f wx0_1 = {W_ih[ri * 2 + 0] * KN1, W_ih[rf * 2 + 0] * KN1};
  const v2f wx1_1 = {W_ih[ri * 2 + 1] * KN1, W_ih[rf * 2 + 1] * KN1};
  const v2f wx0_2 = {W_ih[rg * 2 + 0] * KN2, W_ih[ro * 2 + 0] * KN1};
  const v2f wx1_2 = {W_ih[rg * 2 + 1] * KN2, W_ih[ro * 2 + 1] * KN1};
  v2f wh1[H], wh2[H];
  #pragma unroll
  for (int k = 0; k < H; ++k) {
    wh1[k] = (v2f){W_hh[ri * H + k] * KN1, W_hh[rf * H + k] * KN1};
    wh2[k] = (v2f){W_hh[rg * H + k] * KN2, W_hh[ro * H + k] * KN1};
  }
  const v2f bb1 = {(b_ih[ri] + b_hh[ri]) * KN1, (b_ih[rf] + b_hh[rf]) * KN1};
  const v2f bb2 = {(b_ih[rg] + b_hh[rg]) * KN2, (b_ih[ro] + b_hh[ro]) * KN1};

  float CS = 0.0f, h = 0.0f;          // unit j's scaled cell state & h
  float hg[H] = {0, 0, 0, 0, 0};      // broadcast h vector

  const float2* __restrict__ x2 = (const float2*)x;

  auto step = [&](float2 xv) {
    v2f a1 = bb1, a2 = bb2;
    a1 = __builtin_elementwise_fma((v2f){xv.x, xv.x}, wx0_1, a1);
    a2 = __builtin_elementwise_fma((v2f){xv.x, xv.x}, wx0_2, a2);
    a1 = __builtin_elementwise_fma((v2f){xv.y, xv.y}, wx1_1, a1);
    a2 = __builtin_elementwise_fma((v2f){xv.y, xv.y}, wx1_2, a2);
    #pragma unroll
    for (int k = 0; k < H; ++k) {
      a1 = __builtin_elementwise_fma((v2f){hg[k], hg[k]}, wh1[k], a1);
      a2 = __builtin_elementwise_fma((v2f){hg[k], hg[k]}, wh2[k], a2);
    }
    // Activations: 4 independent exp2+rcp pairs + 1 tanh pair, all local.
    const float si  = frcp(1.0f + fexp2(a1.x));        // sigma(i)
    const float sf  = frcp(1.0f + fexp2(a1.y));        // sigma(f)
    const float rgv = frcp(1.0f + fexp2(a2.x));        // sigma(2 z_g)
    const float so  = frcp(1.0f + fexp2(a2.y));        // sigma(o)
    const float gK  = fmaf(rgv, 2.0f * KN2, -KN2);     // tanh(z_g)*KN2
    CS = fmaf(sf, CS, si * gK);                        // f*CS + i*g*KN2
    const float rt = frcp(1.0f + fexp2(CS));           // sigma(2c)
    h = fmaf(rt, so + so, -so);                        // o*tanh(c)
    // h-broadcast via DPP (VALU pipe). Lanes 4-7 all hold h4 (dups).
    const bool hi = (j & 4) != 0;
    const float hm = DPP(h, 0x141);                    // half-mirror
    hg[4] = hi ? h : hm;
    const float s0 = DPP(h, 0x00), m0 = DPP(s0, 0x141);
    hg[0] = hi ? m0 : s0;
    const float s1 = DPP(h, 0x55), m1 = DPP(s1, 0x141);
    hg[1] = hi ? m1 : s1;
    const float s2 = DPP(h, 0xAA), m2 = DPP(s2, 0x141);
    hg[2] = hi ? m2 : s2;
    const float s3 = DPP(h, 0xFF), m3 = DPP(s3, 0x141);
    hg[3] = hi ? m3 : s3;
  };

  // Ping-pong register prefetch of x, 4 steps deep (~1000 cy ahead).
  constexpr int CH = 4;
  float2 buf0[CH], buf1[CH];
  #pragma unroll
  for (int t = 0; t < CH; ++t) buf0[t] = x2[(size_t)t * B + chain];

  for (int t0 = 0; t0 < S; t0 += 2 * CH) {
    #pragma unroll
    for (int t = 0; t < CH; ++t) buf1[t] = x2[(size_t)(t0 + CH + t) * B + chain];
    #pragma unroll
    for (int t = 0; t < CH; ++t) step(buf0[t]);
    if (t0 + 2 * CH < S) {
      #pragma unroll
      for (int t = 0; t < CH; ++t) buf0[t] = x2[(size_t)(t0 + 2 * CH + t) * B + chain];
    }
    #pragma unroll
    for (int t = 0; t < CH; ++t) step(buf1[t]);
  }

  // out[chain] = sum_j h_j*W_lin[j] + b_lin (butterfly within 8 lanes).
  float pv = (j < H) ? h * W_lin[jm] : 0.0f;
  pv += SWZ(pv, 0x041F);   // xor 1
  pv += SWZ(pv, 0x081F);   // xor 2
  pv += SWZ(pv, 0x101F);   // xor 4
  if (j == 0) out[chain] = pv + b_lin[0];
}

extern "C" void kernel_launch(void* const* d_in, const int* in_sizes, int n_in,
                              void* d_out, int out_size, void* d_ws, size_t ws_size,
                              hipStream_t stream) {
  const float* x     = (const float*)d_in[0];
  const float* W_ih  = (const float*)d_in[1];
  const float* W_hh  = (const float*)d_in[2];
  const float* b_ih  = (const float*)d_in[3];
  const float* b_hh  = (const float*)d_in[4];
  const float* W_lin = (const float*)d_in[5];
  const float* b_lin = (const float*)d_in[6];
  float* out = (float*)d_out;

  const int threads = B * 8;           // 65536 -> 1024 waves -> 1/SIMD
  dim3 grid(threads / 256), block(256);
  hipLaunchKernelGGL(lstm_kernel, grid, block, 0, stream,
                     x, W_ih, W_hh, b_ih, b_hh, W_lin, b_lin, out);
}

// Round 10
// 73.582 us; speedup vs baseline: 1.4455x; 1.0092x over previous
//
#include <hip/hip_runtime.h>

typedef float v2f __attribute__((ext_vector_type(2)));

constexpr int S = 512, B = 8192, H = 5;
constexpr float KN1 = -1.44269504088896340736f;   // -log2(e)
constexpr float KN2 = 2.0f * KN1;                 // -2*log2(e)

__device__ __forceinline__ float fexp2(float x) { return __builtin_amdgcn_exp2f(x); }
__device__ __forceinline__ float frcp(float x)  { return __builtin_amdgcn_rcpf(x); }

// ds_swizzle (epilogue reduction only): imm = xor<<10 | or<<5 | and
#define SWZ(v, imm) __int_as_float(__builtin_amdgcn_ds_swizzle(__float_as_int(v), (imm)))
// DPP (VALU pipe), in-group for 8-aligned 8-lane groups:
//   quad_perm[k,k,k,k] (ctrl k*0x55): broadcast lane k of each 4-quad
//   row_half_mirror (ctrl 0x141):     lane l <-> (l&~7)|(7-(l&7))
#define DPP(v, ctrl) __int_as_float(__builtin_amdgcn_mov_dpp(__float_as_int(v), (ctrl), 0xF, 0xF, false))

// TRANS-THROUGHPUT MODEL (fits R1-R9): wave64 v_exp_f32/v_rcp_f32 cost
// ~32 cy each on a shared 1/16-rate pipe; wall = 32 * trans_instrs * W.
// R9 spent 10 trans/unit-step. This kernel cuts to 7 via common-denominator
// algebra, with E* = exp2(-z* log2e) (g,c rows at -2 log2e):
//   i = 1/Di, f = 1/Df, g = (1-Eg)/Dg  (D* = 1+E*)
//   c' = f c + i g = [c*Di*Dg + (1-Eg)*Df] / (Df*Di*Dg)   -> 3 exp2 + 1 rcp
//   h  = o tanh(c') = (1-Ec)/(Do*Dc)                      -> 2 exp2 + 1 rcp
// Exact algebra (no approximation); cell state kept scaled CS = c*KN2 so
// Ec = exp2(CS) directly. Layout = R9: 8 lanes/chain, lane j owns unit j
// wholly (lanes 5-7 duplicate unit 4 bitwise); only cross-lane op is the
// h-broadcast via quad_perm/half-mirror DPP. 1024 waves = 1 wave/SIMD.
__global__ __launch_bounds__(256, 1) void lstm_kernel(
    const float* __restrict__ x,      // [S,B,2]
    const float* __restrict__ W_ih,   // [4H,2]
    const float* __restrict__ W_hh,   // [4H,H]
    const float* __restrict__ b_ih,   // [4H]
    const float* __restrict__ b_hh,   // [4H]
    const float* __restrict__ W_lin,  // [1,H]
    const float* __restrict__ b_lin,  // [1]
    float* __restrict__ out)          // [B,1]
{
  const int tid   = blockIdx.x * blockDim.x + threadIdx.x;
  const int chain = tid >> 3;
  const int j     = tid & 7;
  const int jm    = (j < H) ? j : H - 1;

  const int ri = jm, rf = H + jm, rg = 2 * H + jm, ro = 3 * H + jm;

  // acc1 = {i-row, f-row} (KN1); acc2 = {g-row (KN2), o-row (KN1)}.
  const v2f wx0_1 = {W_ih[ri * 2 + 0] * KN1, W_ih[rf * 2 + 0] * KN1};
  const v2f wx1_1 = {W_ih[ri * 2 + 1] * KN1, W_ih[rf * 2 + 1] * KN1};
  const v2f wx0_2 = {W_ih[rg * 2 + 0] * KN2, W_ih[ro * 2 + 0] * KN1};
  const v2f wx1_2 = {W_ih[rg * 2 + 1] * KN2, W_ih[ro * 2 + 1] * KN1};
  v2f wh1[H], wh2[H];
  #pragma unroll
  for (int k = 0; k < H; ++k) {
    wh1[k] = (v2f){W_hh[ri * H + k] * KN1, W_hh[rf * H + k] * KN1};
    wh2[k] = (v2f){W_hh[rg * H + k] * KN2, W_hh[ro * H + k] * KN1};
  }
  const v2f bb1 = {(b_ih[ri] + b_hh[ri]) * KN1, (b_ih[rf] + b_hh[rf]) * KN1};
  const v2f bb2 = {(b_ih[rg] + b_hh[rg]) * KN2, (b_ih[ro] + b_hh[ro]) * KN1};

  float CS = 0.0f, h = 0.0f;          // CS = c*KN2 (scaled cell state)
  float hg[H] = {0, 0, 0, 0, 0};      // broadcast h vector

  const float2* __restrict__ x2 = (const float2*)x;

  auto step = [&](float2 xv) {
    v2f a1 = bb1, a2 = bb2;
    a1 = __builtin_elementwise_fma((v2f){xv.x, xv.x}, wx0_1, a1);
    a2 = __builtin_elementwise_fma((v2f){xv.x, xv.x}, wx0_2, a2);
    a1 = __builtin_elementwise_fma((v2f){xv.y, xv.y}, wx1_1, a1);
    a2 = __builtin_elementwise_fma((v2f){xv.y, xv.y}, wx1_2, a2);
    #pragma unroll
    for (int k = 0; k < H; ++k) {
      a1 = __builtin_elementwise_fma((v2f){hg[k], hg[k]}, wh1[k], a1);
      a2 = __builtin_elementwise_fma((v2f){hg[k], hg[k]}, wh2[k], a2);
    }
    // 5 exp2 + 2 rcp per step (was 5 exp2 + 5 rcp).
    const float Ei = fexp2(a1.x);
    const float Ef = fexp2(a1.y);
    const float Eg = fexp2(a2.x);
    const float Eo = fexp2(a2.y);
    const float Di = 1.0f + Ei, Df = 1.0f + Ef;
    const float Dg = 1.0f + Eg, Do = 1.0f + Eo;
    const float P   = Di * Dg;
    const float R3v = frcp(P * Df);                  // 1/(Df*Di*Dg)
    // KN2*(1-Eg) = fma(-KN2, Eg, KN2); scaled numerator keeps CS = c*KN2.
    const float gnum = fmaf(-KN2, Eg, KN2) * Df;     // KN2*(1-Eg)*Df
    const float num  = fmaf(CS, P, gnum);
    CS = num * R3v;                                  // (f*c + i*g)*KN2
    const float Ec = fexp2(CS);                      // exp(-2c)
    const float Dc = 1.0f + Ec;
    const float Rh = frcp(Do * Dc);
    h = (1.0f - Ec) * Rh;                            // o * tanh(c)
    // h-broadcast via DPP (VALU pipe); lanes 4-7 all hold h4 (dups).
    const bool hi = (j & 4) != 0;
    const float hm = DPP(h, 0x141);                  // half-mirror
    hg[4] = hi ? h : hm;
    const float s0 = DPP(h, 0x00), m0 = DPP(s0, 0x141);
    hg[0] = hi ? m0 : s0;
    const float s1 = DPP(h, 0x55), m1 = DPP(s1, 0x141);
    hg[1] = hi ? m1 : s1;
    const float s2 = DPP(h, 0xAA), m2 = DPP(s2, 0x141);
    hg[2] = hi ? m2 : s2;
    const float s3 = DPP(h, 0xFF), m3 = DPP(s3, 0x141);
    hg[3] = hi ? m3 : s3;
  };

  // Ping-pong register prefetch of x, 4 steps deep.
  constexpr int CH = 4;
  float2 buf0[CH], buf1[CH];
  #pragma unroll
  for (int t = 0; t < CH; ++t) buf0[t] = x2[(size_t)t * B + chain];

  for (int t0 = 0; t0 < S; t0 += 2 * CH) {
    #pragma unroll
    for (int t = 0; t < CH; ++t) buf1[t] = x2[(size_t)(t0 + CH + t) * B + chain];
    #pragma unroll
    for (int t = 0; t < CH; ++t) step(buf0[t]);
    if (t0 + 2 * CH < S) {
      #pragma unroll
      for (int t = 0; t < CH; ++t) buf0[t] = x2[(size_t)(t0 + 2 * CH + t) * B + chain];
    }
    #pragma unroll
    for (int t = 0; t < CH; ++t) step(buf1[t]);
  }

  // out[chain] = sum_j h_j*W_lin[j] + b_lin (butterfly within 8 lanes).
  float pv = (j < H) ? h * W_lin[jm] : 0.0f;
  pv += SWZ(pv, 0x041F);   // xor 1
  pv += SWZ(pv, 0x081F);   // xor 2
  pv += SWZ(pv, 0x101F);   // xor 4
  if (j == 0) out[chain] = pv + b_lin[0];
}

extern "C" void kernel_launch(void* const* d_in, const int* in_sizes, int n_in,
                              void* d_out, int out_size, void* d_ws, size_t ws_size,
                              hipStream_t stream) {
  const float* x     = (const float*)d_in[0];
  const float* W_ih  = (const float*)d_in[1];
  const float* W_hh  = (const float*)d_in[2];
  const float* b_ih  = (const float*)d_in[3];
  const float* b_hh  = (const float*)d_in[4];
  const float* W_lin = (const float*)d_in[5];
  const float* b_lin = (const float*)d_in[6];
  float* out = (float*)d_out;

  const int threads = B * 8;           // 65536 -> 1024 waves -> 1/SIMD
  dim3 grid(threads / 256), block(256);
  hipLaunchKernelGGL(lstm_kernel, grid, block, 0, stream,
                     x, W_ih, W_hh, b_ih, b_hh, W_lin, b_lin, out);
}